// Round 5
// baseline (239.500 us; speedup 1.0000x reference)
//
#include <hip/hip_runtime.h>
#include <hip/hip_bf16.h>

#define B_    8
#define N_    1024
#define C_    512
#define H_    4
#define HD_   128
#define BN_   (B_ * N_)      // 8192
#define QKVC_ 1536
#define SCALE_ 0.08838834764831845f  // 128^-0.5

typedef __bf16 bf16;
typedef __bf16 bf16x8 __attribute__((ext_vector_type(8)));
typedef float  floatx4 __attribute__((ext_vector_type(4)));

__device__ __forceinline__ void gload_lds16(const bf16* g, bf16* l) {
    __builtin_amdgcn_global_load_lds(
        (const __attribute__((address_space(1))) void*)g,
        (__attribute__((address_space(3))) void*)l, 16, 0, 0);
}

__device__ __forceinline__ bf16x8 cvt8(float4 f0, float4 f1) {
    bf16x8 v;
    v[0] = (bf16)f0.x; v[1] = (bf16)f0.y; v[2] = (bf16)f0.z; v[3] = (bf16)f0.w;
    v[4] = (bf16)f1.x; v[5] = (bf16)f1.y; v[6] = (bf16)f1.z; v[7] = (bf16)f1.w;
    return v;
}

// ---------------------------------------------------------------------------
// Kernel 0: fp32 -> bf16 for weights only.
// ---------------------------------------------------------------------------
__global__ __launch_bounds__(256) void cvt_w(const float* __restrict__ wq, bf16* __restrict__ wqb,
                                             const float* __restrict__ wp, bf16* __restrict__ wpb) {
    int id = blockIdx.x * 256 + threadIdx.x;   // 131072 threads
    const float* s; bf16* d; int off;
    if (id < 98304) { s = wq; d = wqb; off = id; }
    else            { s = wp; d = wpb; off = id - 98304; }
    const float4* sp = (const float4*)s + (size_t)off * 2;
    ((bf16x8*)d)[off] = cvt8(sp[0], sp[1]);
}

// ---------------------------------------------------------------------------
// qkv GEMM: C[m][n] = sum_k x[m][k] * Wq[n][k], fp32 A staged inline->bf16.
// XOR chunk swizzle (global chunk c of row r at LDS chunk c^(r&7)).
// ---------------------------------------------------------------------------
__global__ __launch_bounds__(256) void qkv_gemm(const float* __restrict__ A,
                                                const bf16* __restrict__ Bw,
                                                bf16* __restrict__ Cout) {
    const int t = threadIdx.x;
    const int wave = t >> 6, lane = t & 63;
    const int quad = lane >> 4, l16 = lane & 15;
    const int ro = lane >> 3;
    const int ch = (lane & 7) ^ ro;

    const int m_base = blockIdx.x * 128;
    const int n_base = blockIdx.y * 128;
    const int wave_r = (wave & 1) * 64;
    const int wave_c = (wave >> 1) * 64;

    __shared__ bf16 As[128 * 64];
    __shared__ bf16 Bs[128 * 64];

    floatx4 acc[4][4] = {};

    const int ar = t >> 1;
    const int ac0 = (t & 1) * 4;

    for (int k0 = 0; k0 < 512; k0 += 64) {
        __syncthreads();
        {
            const float* src = A + (size_t)(m_base + ar) * 512 + k0;
            float4 f[8];
#pragma unroll
            for (int c = 0; c < 4; c++) {
                f[2 * c]     = *(const float4*)(src + (ac0 + c) * 8);
                f[2 * c + 1] = *(const float4*)(src + (ac0 + c) * 8 + 4);
            }
#pragma unroll
            for (int c = 0; c < 4; c++)
                *(bf16x8*)&As[ar * 64 + (((ac0 + c) ^ (ar & 7)) * 8)] =
                    cvt8(f[2 * c], f[2 * c + 1]);
        }
#pragma unroll
        for (int j = 0; j < 4; j++) {
            int r0 = (wave * 4 + j) * 8;
            gload_lds16(Bw + (size_t)(n_base + r0 + ro) * 512 + k0 + ch * 8,
                        Bs + r0 * 64);
        }
        __syncthreads();

#pragma unroll
        for (int kk = 0; kk < 2; kk++) {
            const int kc = kk * 4 + quad;
            bf16x8 af[4], bfr[4];
#pragma unroll
            for (int mt = 0; mt < 4; mt++) {
                int r = wave_r + mt * 16 + l16;
                af[mt] = *(const bf16x8*)&As[r * 64 + ((kc ^ (r & 7)) * 8)];
            }
#pragma unroll
            for (int nt = 0; nt < 4; nt++) {
                int r = wave_c + nt * 16 + l16;
                bfr[nt] = *(const bf16x8*)&Bs[r * 64 + ((kc ^ (r & 7)) * 8)];
            }
#pragma unroll
            for (int mt = 0; mt < 4; mt++)
#pragma unroll
                for (int nt = 0; nt < 4; nt++)
                    acc[mt][nt] = __builtin_amdgcn_mfma_f32_16x16x32_bf16(
                        af[mt], bfr[nt], acc[mt][nt], 0, 0, 0);
        }
    }

#pragma unroll
    for (int nt = 0; nt < 4; nt++) {
        int col = n_base + wave_c + nt * 16 + l16;
#pragma unroll
        for (int mt = 0; mt < 4; mt++)
#pragma unroll
            for (int r = 0; r < 4; r++) {
                int row = m_base + wave_r + mt * 16 + quad * 4 + r;
                Cout[(size_t)row * QKVC_ + col] = (bf16)acc[mt][nt][r];
            }
    }
}

// ---------------------------------------------------------------------------
// Fused CIM flash attention, split-K (2 x 512 keys), 32 q-rows per wave
// (2 row-groups share every K/V fragment read).  Unnormalized O + (m,l).
// ---------------------------------------------------------------------------
__global__ __launch_bounds__(256) void flash_attn(const bf16* __restrict__ qkv,
                                                  const float* __restrict__ w_main,
                                                  const float* __restrict__ w_rest,
                                                  bf16* __restrict__ po,
                                                  float* __restrict__ ml) {
    const int b = blockIdx.z >> 1, split = blockIdx.z & 1;
    const int head = blockIdx.y;
    const int n0 = blockIdx.x * 128;
    const int t = threadIdx.x;
    const int wave = t >> 6, lane = t & 63;
    const int quad = lane >> 4, l16 = lane & 15;

    float qs[H_];
#pragma unroll
    for (int j = 0; j < H_; j++) {
        float mij = (j == head) ? w_main[head]
                                : w_rest[head * (H_ - 1) + (j - (j > head ? 1 : 0))];
        qs[j] = mij * SCALE_;
    }

    __shared__ bf16 Kt[32 * 512];
    __shared__ bf16 Vt[128][40];
    __shared__ bf16 Pb[4][2][16][40];

    bf16x8 qf[2][16];
#pragma unroll
    for (int g = 0; g < 2; g++) {
        const int qrow = n0 + g * 64 + wave * 16 + l16;
        const bf16* qbase = qkv + (size_t)(b * N_ + qrow) * QKVC_;
#pragma unroll
        for (int kk = 0; kk < 16; kk++) {
            int kg = kk * 32 + quad * 8;
            bf16x8 v = *(const bf16x8*)(qbase + kg);
            float sc = qs[kg >> 7];
            bf16x8 q;
#pragma unroll
            for (int j = 0; j < 8; j++) q[j] = (bf16)((float)v[j] * sc);
            qf[g][kk] = q;
        }
    }

    bf16x8 vones;
#pragma unroll
    for (int j = 0; j < 8; j++) vones[j] = (bf16)1.0f;

    floatx4 o[2][8] = {};
    float mrow[2][4], lrow[2][4];
#pragma unroll
    for (int g = 0; g < 2; g++)
#pragma unroll
        for (int r = 0; r < 4; r++) { mrow[g][r] = -1e30f; lrow[g][r] = 0.f; }

    const bf16* kvbase = qkv + (size_t)(b * N_) * QKVC_;
    const int vg = t & 3, vp = t >> 2;
    const int m_begin = split * 512;

    for (int m0 = m_begin; m0 < m_begin + 512; m0 += 32) {
        __syncthreads();
#pragma unroll
        for (int j = 0; j < 8; j++) {
            int r = wave * 8 + j;
            gload_lds16(kvbase + (size_t)(m0 + r) * QKVC_ + 512 + ((lane ^ (r & 7)) << 3),
                        Kt + r * 512);
        }
        {
            const bf16* vs = kvbase + (size_t)(m0 + 8 * vg) * QKVC_ + 1024 + head * HD_ + 2 * vp;
            unsigned int dw[8];
#pragma unroll
            for (int j = 0; j < 8; j++)
                dw[j] = *(const unsigned int*)(vs + (size_t)j * QKVC_);
            uint4 lo, hi;
            lo.x = (dw[0] & 0xffffu) | (dw[1] << 16);
            lo.y = (dw[2] & 0xffffu) | (dw[3] << 16);
            lo.z = (dw[4] & 0xffffu) | (dw[5] << 16);
            lo.w = (dw[6] & 0xffffu) | (dw[7] << 16);
            hi.x = (dw[0] >> 16) | (dw[1] & 0xffff0000u);
            hi.y = (dw[2] >> 16) | (dw[3] & 0xffff0000u);
            hi.z = (dw[4] >> 16) | (dw[5] & 0xffff0000u);
            hi.w = (dw[6] >> 16) | (dw[7] & 0xffff0000u);
            *(uint4*)&Vt[2 * vp][8 * vg] = lo;
            *(uint4*)&Vt[2 * vp + 1][8 * vg] = hi;
        }
        __syncthreads();

        floatx4 s[2][2] = {};
#pragma unroll
        for (int kk = 0; kk < 16; kk++) {
            bf16x8 kb[2];
#pragma unroll
            for (int nt = 0; nt < 2; nt++) {
                int r = nt * 16 + l16;
                kb[nt] = *(const bf16x8*)&Kt[r * 512 + (((kk * 4 + quad) ^ (r & 7)) << 3)];
            }
#pragma unroll
            for (int g = 0; g < 2; g++)
#pragma unroll
                for (int nt = 0; nt < 2; nt++)
                    s[g][nt] = __builtin_amdgcn_mfma_f32_16x16x32_bf16(
                        qf[g][kk], kb[nt], s[g][nt], 0, 0, 0);
        }

#pragma unroll
        for (int g = 0; g < 2; g++)
#pragma unroll
            for (int r = 0; r < 4; r++) {
                float mx = fmaxf(s[g][0][r], s[g][1][r]);
#pragma unroll
                for (int off = 1; off < 16; off <<= 1) mx = fmaxf(mx, __shfl_xor(mx, off));
                float mnew = fmaxf(mrow[g][r], mx);
                float alpha = __expf(mrow[g][r] - mnew);
                mrow[g][r] = mnew;
                s[g][0][r] = __expf(s[g][0][r] - mnew);
                s[g][1][r] = __expf(s[g][1][r] - mnew);
                lrow[g][r] *= alpha;
#pragma unroll
                for (int nt = 0; nt < 8; nt++) o[g][nt][r] *= alpha;
            }

#pragma unroll
        for (int g = 0; g < 2; g++)
#pragma unroll
            for (int nt = 0; nt < 2; nt++)
#pragma unroll
                for (int r = 0; r < 4; r++)
                    Pb[wave][g][quad * 4 + r][nt * 16 + l16] = (bf16)s[g][nt][r];

        bf16x8 pf[2];
#pragma unroll
        for (int g = 0; g < 2; g++) {
            pf[g] = *(const bf16x8*)&Pb[wave][g][l16][quad * 8];
            floatx4 s9 = __builtin_amdgcn_mfma_f32_16x16x32_bf16(
                pf[g], vones, (floatx4){0.f, 0.f, 0.f, 0.f}, 0, 0, 0);
#pragma unroll
            for (int r = 0; r < 4; r++) lrow[g][r] += s9[r];
        }

#pragma unroll
        for (int nt = 0; nt < 8; nt++) {
            bf16x8 vf = *(const bf16x8*)&Vt[nt * 16 + l16][quad * 8];
            o[0][nt] = __builtin_amdgcn_mfma_f32_16x16x32_bf16(pf[0], vf, o[0][nt], 0, 0, 0);
            o[1][nt] = __builtin_amdgcn_mfma_f32_16x16x32_bf16(pf[1], vf, o[1][nt], 0, 0, 0);
        }
    }

    bf16* pod = po + (size_t)split * BN_ * C_;
#pragma unroll
    for (int g = 0; g < 2; g++)
#pragma unroll
        for (int r = 0; r < 4; r++) {
            int row = n0 + g * 64 + wave * 16 + quad * 4 + r;
            bf16* dst = pod + (size_t)(b * N_ + row) * C_ + head * HD_;
#pragma unroll
            for (int nt = 0; nt < 8; nt++)
                dst[nt * 16 + l16] = (bf16)o[g][nt][r];
            if (l16 == 0) {
                size_t idx = ((size_t)split * BN_ + b * N_ + row) * H_ + head;
                ml[idx * 2]     = mrow[g][r];
                ml[idx * 2 + 1] = lrow[g][r];
            }
        }
}

// ---------------------------------------------------------------------------
// proj GEMM with fused split-merge in A-staging.
// ---------------------------------------------------------------------------
__global__ __launch_bounds__(256) void proj_gemm(const bf16* __restrict__ po,
                                                 const float* __restrict__ ml,
                                                 const bf16* __restrict__ Bw,
                                                 const float* __restrict__ bias,
                                                 float* __restrict__ Cout) {
    const int t = threadIdx.x;
    const int wave = t >> 6, lane = t & 63;
    const int quad = lane >> 4, l16 = lane & 15;
    const int ro = lane >> 3;
    const int ch = (lane & 7) ^ ro;

    const int m_base = blockIdx.x * 128;
    const int n_base = blockIdx.y * 64;
    const int wave_r = (wave & 1) * 64;
    const int wave_c = (wave >> 1) * 32;

    __shared__ bf16 As[128 * 64];
    __shared__ bf16 Bs[64 * 64];

    floatx4 acc[4][2] = {};

    const int ar = t >> 1;
    const int ac0 = (t & 1) * 4;

    for (int k0 = 0; k0 < 512; k0 += 64) {
        __syncthreads();
        {
            const int token = m_base + ar;
            const int hd = k0 >> 7;
            const float2 ml0 = *(const float2*)&ml[((size_t)token * H_ + hd) * 2];
            const float2 ml1 = *(const float2*)&ml[((size_t)(BN_ + token) * H_ + hd) * 2];
            float ms = fmaxf(ml0.x, ml1.x);
            float e0 = __expf(ml0.x - ms), e1 = __expf(ml1.x - ms);
            float inv = 1.0f / (e0 * ml0.y + e1 * ml1.y);
            float w0 = e0 * inv, w1 = e1 * inv;
            const bf16* p0 = po + (size_t)token * C_ + k0;
            const bf16* p1 = p0 + (size_t)BN_ * C_;
#pragma unroll
            for (int c = 0; c < 4; c++) {
                bf16x8 a = *(const bf16x8*)(p0 + (ac0 + c) * 8);
                bf16x8 bq = *(const bf16x8*)(p1 + (ac0 + c) * 8);
                bf16x8 v;
#pragma unroll
                for (int j = 0; j < 8; j++)
                    v[j] = (bf16)((float)a[j] * w0 + (float)bq[j] * w1);
                *(bf16x8*)&As[ar * 64 + (((ac0 + c) ^ (ar & 7)) * 8)] = v;
            }
        }
#pragma unroll
        for (int j = 0; j < 2; j++) {
            int r0 = (wave * 2 + j) * 8;
            gload_lds16(Bw + (size_t)(n_base + r0 + ro) * 512 + k0 + ch * 8,
                        Bs + r0 * 64);
        }
        __syncthreads();

#pragma unroll
        for (int kk = 0; kk < 2; kk++) {
            const int kc = kk * 4 + quad;
            bf16x8 af[4], bfr[2];
#pragma unroll
            for (int mt = 0; mt < 4; mt++) {
                int r = wave_r + mt * 16 + l16;
                af[mt] = *(const bf16x8*)&As[r * 64 + ((kc ^ (r & 7)) * 8)];
            }
#pragma unroll
            for (int nt = 0; nt < 2; nt++) {
                int r = wave_c + nt * 16 + l16;
                bfr[nt] = *(const bf16x8*)&Bs[r * 64 + ((kc ^ (r & 7)) * 8)];
            }
#pragma unroll
            for (int mt = 0; mt < 4; mt++)
#pragma unroll
                for (int nt = 0; nt < 2; nt++)
                    acc[mt][nt] = __builtin_amdgcn_mfma_f32_16x16x32_bf16(
                        af[mt], bfr[nt], acc[mt][nt], 0, 0, 0);
        }
    }

#pragma unroll
    for (int nt = 0; nt < 2; nt++) {
        int col = n_base + wave_c + nt * 16 + l16;
        float bi = bias[col];
#pragma unroll
        for (int mt = 0; mt < 4; mt++)
#pragma unroll
            for (int r = 0; r < 4; r++) {
                int row = m_base + wave_r + mt * 16 + quad * 4 + r;
                Cout[(size_t)row * C_ + col] = acc[mt][nt][r] + bi;
            }
    }
}

// ---------------------------------------------------------------------------
extern "C" void kernel_launch(void* const* d_in, const int* in_sizes, int n_in,
                              void* d_out, int out_size, void* d_ws, size_t ws_size,
                              hipStream_t stream) {
    const float* x      = (const float*)d_in[0];
    const float* w_qkv  = (const float*)d_in[1];
    const float* w_proj = (const float*)d_in[2];
    const float* b_proj = (const float*)d_in[3];
    const float* w_main = (const float*)d_in[4];
    const float* w_rest = (const float*)d_in[5];
    float* out = (float*)d_out;

    bf16* qkv = (bf16*)d_ws;                           // [8192,1536]
    bf16* wqb = qkv + (size_t)BN_ * QKVC_;             // [1536,512]
    bf16* wpb = wqb + 3 * C_ * C_;                     // [512,512]
    bf16* po  = wpb + C_ * C_;                         // 2 x [8192,512]
    float* ml = (float*)(po + (size_t)2 * BN_ * C_);   // 2 x [32768][2]

    cvt_w<<<512, 256, 0, stream>>>(w_qkv, wqb, w_proj, wpb);
    qkv_gemm<<<dim3(64, 12), 256, 0, stream>>>(x, wqb, qkv);
    flash_attn<<<dim3(N_ / 128, H_, B_ * 2), 256, 0, stream>>>(qkv, w_main, w_rest, po, ml);
    proj_gemm<<<dim3(64, 8), 256, 0, stream>>>(po, ml, wpb, b_proj, out);
}